// Round 14
// baseline (297.004 us; speedup 1.0000x reference)
//
#include <hip/hip_runtime.h>
#include <hip/hip_bf16.h>

#define DIM 64
#define NEG 0.01f
#define CHUNK 8192
#define BINT 512
#define NBMAX 640   // >= ceil(150000/256) = 586 buckets
#define CAP 9216    // fixed slots per bucket (mean 6827 + pad ~900, sigma ~85 -> big margin)

typedef float f32x4 __attribute__((ext_vector_type(4)));

// exclusive scan of in[0..n) -> out[0..n), tmp[T] scratch, T threads
template <int T>
__device__ __forceinline__ void block_exscan(int* __restrict__ in, int* __restrict__ out,
                                             int* __restrict__ tmp, int n, int tid) {
    int carry = 0;
    for (int base = 0; base < n; base += T) {
        int i = base + tid;
        int v = (i < n) ? in[i] : 0;
        tmp[tid] = v;
        __syncthreads();
        for (int o = 1; o < T; o <<= 1) {
            int u = (tid >= o) ? tmp[tid - o] : 0;
            __syncthreads();
            tmp[tid] += u;
            __syncthreads();
        }
        if (i < n) out[i] = carry + tmp[tid] - v;
        carry += tmp[T - 1];
        __syncthreads();
    }
}

__device__ __forceinline__ float bflo(unsigned int u) { return __uint_as_float(u << 16); }
__device__ __forceinline__ float bfhi(unsigned int u) { return __uint_as_float(u & 0xFFFF0000u); }

// --- bin edges into fixed per-bucket regions (bucket = dst>>8), packed (dlow<<24 | src);
//     block 0 also zeroes the sentinel hh row ---
__global__ void kA_bin(const int* __restrict__ src, const int* __restrict__ dst, int E,
                       int* __restrict__ bucketCursor, int* __restrict__ binned, int nb,
                       unsigned short* __restrict__ hhRaw, int N) {
    __shared__ int bCnt[NBMAX];
    __shared__ int bBase[NBMAX];
    __shared__ int bGBase[NBMAX];
    __shared__ int tmp[BINT];
    __shared__ int stP[CHUNK];
    __shared__ unsigned short stB[CHUNK];
    int tid = threadIdx.x;
    if (blockIdx.x == 0 && tid < 64) hhRaw[(size_t)N * 64 + tid] = 0;  // sentinel zero row
    int e0 = blockIdx.x * CHUNK;
    int nE = min(CHUNK, E - e0);
    int nI4 = nE >> 2;
    int rem = nE & 3;
    const int4* s4 = (const int4*)(src + e0);
    const int4* d4 = (const int4*)(dst + e0);

    for (int b = tid; b < nb; b += BINT) bCnt[b] = 0;
    __syncthreads();
    for (int i = tid; i < nI4; i += BINT) {
        int4 d = d4[i];
        atomicAdd(&bCnt[d.x >> 8], 1);
        atomicAdd(&bCnt[d.y >> 8], 1);
        atomicAdd(&bCnt[d.z >> 8], 1);
        atomicAdd(&bCnt[d.w >> 8], 1);
    }
    if (tid < rem) atomicAdd(&bCnt[dst[e0 + (nI4 << 2) + tid] >> 8], 1);
    __syncthreads();
    block_exscan<BINT>(bCnt, bBase, tmp, nb, tid);
    for (int b = tid; b < nb; b += BINT) {
        int c = bCnt[b];
        if (c) bGBase[b] = atomicAdd(&bucketCursor[b], c);
        bCnt[b] = 0;
    }
    __syncthreads();
    for (int i = tid; i < nI4; i += BINT) {
        int4 s = s4[i];
        int4 d = d4[i];
#define PLACE1(SS, DD) { int b_ = (DD) >> 8; int r_ = atomicAdd(&bCnt[b_], 1); \
                         int p_ = bBase[b_] + r_; stP[p_] = (((DD) & 255) << 24) | (SS); \
                         stB[p_] = (unsigned short)b_; }
        PLACE1(s.x, d.x) PLACE1(s.y, d.y) PLACE1(s.z, d.z) PLACE1(s.w, d.w)
    }
    if (tid < rem) {
        int e = e0 + (nI4 << 2) + tid;
        int s = src[e], d = dst[e];
        PLACE1(s, d)
    }
#undef PLACE1
    __syncthreads();
    for (int i = tid; i < nE; i += BINT) {
        int b = stB[i];
        int rel = bGBase[b] + (i - bBase[b]);
        if (rel < CAP) binned[(size_t)b * CAP + rel] = stP[i];
    }
}

// --- per-bucket place: LDS-staged; emits meta{begIdx,paddedCnt,dinv}, dinv, padded csr ---
__global__ void kB_place(const int* __restrict__ binned, const int* __restrict__ bucketCursor,
                         int4* __restrict__ meta, float* __restrict__ dinv,
                         int* __restrict__ csr, int N) {
    __shared__ int st[CAP];
    __shared__ int nodeCnt[256];
    __shared__ int nodeOff[256];
    __shared__ int tmp[256];
    int tid = threadIdx.x;
    int b = blockIdx.x;
    int cntE = min(bucketCursor[b], CAP);
    const int* bb = binned + (size_t)b * CAP;
    for (int e = tid; e < cntE; e += 256) st[e] = bb[e];
    nodeCnt[tid] = 0;
    __syncthreads();
    for (int e = tid; e < cntE; e += 256) atomicAdd(&nodeCnt[((unsigned int)st[e]) >> 24], 1);
    __syncthreads();
    int myc = nodeCnt[tid];
    int mypc = (myc + 7) & ~7;  // pad rows to multiple of 8
    nodeCnt[tid] = mypc;
    __syncthreads();
    block_exscan<256>(nodeCnt, nodeOff, tmp, 256, tid);
    int myoff = nodeOff[tid];
    int node = (b << 8) + tid;
    int base = b * CAP;
    if (node < N) {
        float dv = rsqrtf((float)myc + 1.0f);
        dinv[node] = dv;
        meta[node] = make_int4(base + myoff, mypc, __float_as_int(dv), 0);
        for (int q = myc; q < mypc; ++q) csr[base + myoff + q] = N << 7;  // sentinel -> zero row
    }
    __syncthreads();
    for (int e = tid; e < cntE; e += 256) {
        unsigned int p = (unsigned int)st[e];
        int r = atomicAdd(&nodeOff[p >> 24], 1);
        csr[base + r] = (int)(p & 0xFFFFFF) << 7;
    }
}

// --- hh(bf16) = (x @ W) * dinv[row]; LDS-tiled 4x4/thread (round-13, proven) ---
#define XSP 68
__global__ void __launch_bounds__(256, 4) k_linear(
                         const float* __restrict__ x, int xstride,
                         const float* __restrict__ W, const float* __restrict__ dinv,
                         __hip_bfloat16* __restrict__ hh, int N) {
    __shared__ float Ws[DIM][DIM];   // 16 KB
    __shared__ float xs[64][XSP];    // 17 KB (padded)
    int t = threadIdx.x;
    int row0 = blockIdx.x * 64;
#pragma unroll
    for (int k = 0; k < 16; ++k) {
        int idx = t + k * 256;
        Ws[idx >> 6][idx & 63] = W[idx];
    }
#pragma unroll
    for (int g = 0; g < 16; ++g) {
        int r = (t >> 6) + g * 4;
        int row = row0 + r;
        xs[r][t & 63] = (row < N) ? x[(size_t)row * xstride + (t & 63)] : 0.f;
    }
    __syncthreads();

    int c0 = (t & 15) * 4;
    int r0 = (t >> 4) * 4;
    float4 accR0 = {0.f, 0.f, 0.f, 0.f};
    float4 accR1 = {0.f, 0.f, 0.f, 0.f};
    float4 accR2 = {0.f, 0.f, 0.f, 0.f};
    float4 accR3 = {0.f, 0.f, 0.f, 0.f};

#define ROWFMA(ACC, XV) \
    ACC.x = fmaf(XV.x, w0.x, ACC.x); ACC.y = fmaf(XV.x, w0.y, ACC.y); \
    ACC.z = fmaf(XV.x, w0.z, ACC.z); ACC.w = fmaf(XV.x, w0.w, ACC.w); \
    ACC.x = fmaf(XV.y, w1.x, ACC.x); ACC.y = fmaf(XV.y, w1.y, ACC.y); \
    ACC.z = fmaf(XV.y, w1.z, ACC.z); ACC.w = fmaf(XV.y, w1.w, ACC.w); \
    ACC.x = fmaf(XV.z, w2.x, ACC.x); ACC.y = fmaf(XV.z, w2.y, ACC.y); \
    ACC.z = fmaf(XV.z, w2.z, ACC.z); ACC.w = fmaf(XV.z, w2.w, ACC.w); \
    ACC.x = fmaf(XV.w, w3.x, ACC.x); ACC.y = fmaf(XV.w, w3.y, ACC.y); \
    ACC.z = fmaf(XV.w, w3.z, ACC.z); ACC.w = fmaf(XV.w, w3.w, ACC.w);

#pragma unroll 1
    for (int k4 = 0; k4 < 16; ++k4) {
        int k = k4 * 4;
        float4 xv0 = *(const float4*)&xs[r0 + 0][k];
        float4 xv1 = *(const float4*)&xs[r0 + 1][k];
        float4 xv2 = *(const float4*)&xs[r0 + 2][k];
        float4 xv3 = *(const float4*)&xs[r0 + 3][k];
        float4 w0 = *(const float4*)&Ws[k + 0][c0];
        float4 w1 = *(const float4*)&Ws[k + 1][c0];
        float4 w2 = *(const float4*)&Ws[k + 2][c0];
        float4 w3 = *(const float4*)&Ws[k + 3][c0];
        ROWFMA(accR0, xv0)
        ROWFMA(accR1, xv1)
        ROWFMA(accR2, xv2)
        ROWFMA(accR3, xv3)
    }
#undef ROWFMA

#define WRITEROW(ACC, J) { \
    int row = row0 + r0 + J; \
    if (row < N) { \
        float dv = dinv[row]; \
        ushort4 o; \
        o.x = (unsigned short)(__bfloat16_as_ushort(__float2bfloat16(ACC.x * dv))); \
        o.y = (unsigned short)(__bfloat16_as_ushort(__float2bfloat16(ACC.y * dv))); \
        o.z = (unsigned short)(__bfloat16_as_ushort(__float2bfloat16(ACC.z * dv))); \
        o.w = (unsigned short)(__bfloat16_as_ushort(__float2bfloat16(ACC.w * dv))); \
        *(ushort4*)((char*)hh + (size_t)row * 128 + c0 * 2) = o; \
    } }
    WRITEROW(accR0, 0)
    WRITEROW(accR1, 1)
    WRITEROW(accR2, 2)
    WRITEROW(accR3, 3)
#undef WRITEROW
}

// --- gather v3: 4 edges per payload instr (quarter-waves, uint2/lane), nt index/store ---
__global__ void k_gather(const int4* __restrict__ meta, const int* __restrict__ csr,
                         const char* __restrict__ hhB, const float* __restrict__ bias,
                         float* __restrict__ out, int colOff, int N) {
    int node = blockIdx.x * 4 + (threadIdx.x >> 6);
    if (node >= N) return;
    int lane = threadIdx.x & 63;
    int q = lane >> 4;     // quarter 0..3 -> edge k+q
    int li = lane & 15;    // lane-in-quarter -> features 4li..4li+3
    int4 m = meta[node];
    int beg = m.x;
    int pc = m.y;          // multiple of 8
    float di = __int_as_float(m.z);
    int fb = li << 3;      // feature byte offset

    const int* p = csr + beg + q;
    float a00 = 0.f, a01 = 0.f, a02 = 0.f, a03 = 0.f;
    float a10 = 0.f, a11 = 0.f, a12 = 0.f, a13 = 0.f;

    int k = 0;
    for (; k + 16 <= pc; k += 16) {
        int o0 = __builtin_nontemporal_load(p);
        int o1 = __builtin_nontemporal_load(p + 4);
        int o2 = __builtin_nontemporal_load(p + 8);
        int o3 = __builtin_nontemporal_load(p + 12);
        p += 16;
        uint2 u0 = *(const uint2*)(hhB + (unsigned int)o0 + fb);
        uint2 u1 = *(const uint2*)(hhB + (unsigned int)o1 + fb);
        uint2 u2 = *(const uint2*)(hhB + (unsigned int)o2 + fb);
        uint2 u3 = *(const uint2*)(hhB + (unsigned int)o3 + fb);
        a00 += bflo(u0.x); a01 += bfhi(u0.x); a02 += bflo(u0.y); a03 += bfhi(u0.y);
        a10 += bflo(u1.x); a11 += bfhi(u1.x); a12 += bflo(u1.y); a13 += bfhi(u1.y);
        a00 += bflo(u2.x); a01 += bfhi(u2.x); a02 += bflo(u2.y); a03 += bfhi(u2.y);
        a10 += bflo(u3.x); a11 += bfhi(u3.x); a12 += bflo(u3.y); a13 += bfhi(u3.y);
    }
    if (k < pc) {  // remaining 8 (pc % 16 == 8)
        int o0 = __builtin_nontemporal_load(p);
        int o1 = __builtin_nontemporal_load(p + 4);
        uint2 u0 = *(const uint2*)(hhB + (unsigned int)o0 + fb);
        uint2 u1 = *(const uint2*)(hhB + (unsigned int)o1 + fb);
        a00 += bflo(u0.x); a01 += bfhi(u0.x); a02 += bflo(u0.y); a03 += bfhi(u0.y);
        a10 += bflo(u1.x); a11 += bfhi(u1.x); a12 += bflo(u1.y); a13 += bfhi(u1.y);
    }
    float f0 = a00 + a10;
    float f1 = a01 + a11;
    float f2 = a02 + a12;
    float f3 = a03 + a13;
    f0 += __shfl_xor(f0, 16); f0 += __shfl_xor(f0, 32);
    f1 += __shfl_xor(f1, 16); f1 += __shfl_xor(f1, 32);
    f2 += __shfl_xor(f2, 16); f2 += __shfl_xor(f2, 32);
    f3 += __shfl_xor(f3, 16); f3 += __shfl_xor(f3, 32);
    if (lane < 16) {
        uint2 su = *(const uint2*)(hhB + ((size_t)node << 7) + fb);  // self row
        f0 += bflo(su.x); f1 += bfhi(su.x); f2 += bflo(su.y); f3 += bfhi(su.y);
        float4 bb = ((const float4*)bias)[li];
        f0 = f0 * di + bb.x;
        f1 = f1 * di + bb.y;
        f2 = f2 * di + bb.z;
        f3 = f3 * di + bb.w;
        f0 = f0 > 0.f ? f0 : f0 * NEG;
        f1 = f1 > 0.f ? f1 : f1 * NEG;
        f2 = f2 > 0.f ? f2 : f2 * NEG;
        f3 = f3 > 0.f ? f3 : f3 * NEG;
        f32x4 o = {f0, f1, f2, f3};
        __builtin_nontemporal_store(o, (f32x4*)(out + (size_t)node * 128 + colOff + (li << 2)));
    }
}

extern "C" void kernel_launch(void* const* d_in, const int* in_sizes, int n_in,
                              void* d_out, int out_size, void* d_ws, size_t ws_size,
                              hipStream_t stream) {
    const int* edge = (const int*)d_in[0];
    const float* x0 = (const float*)d_in[1];
    const float* W1 = (const float*)d_in[2];
    const float* b1 = (const float*)d_in[3];
    const float* W2 = (const float*)d_in[4];
    const float* b2 = (const float*)d_in[5];
    float* out = (float*)d_out;

    int E = in_sizes[0] / 2;
    int N = in_sizes[1] / DIM;
    const int* src = edge;
    const int* dst = edge + E;
    int nb = (N + 255) >> 8;

    char* p = (char*)d_ws;
    auto alloc = [&](size_t bytes) {
        char* r = p;
        p += (bytes + 255) & ~(size_t)255;
        return r;
    };
    int* bucketCursor = (int*)alloc((size_t)nb * 4);
    float* dinv       = (float*)alloc((size_t)N * 4);
    int4* meta        = (int4*)alloc((size_t)N * 16);
    int* csr          = (int*)alloc((size_t)nb * CAP * 4);
    int* binned       = (int*)alloc((size_t)nb * CAP * 4);
    __hip_bfloat16* hh = (__hip_bfloat16*)alloc(((size_t)N + 1) * DIM * 2);

    int nrow_blocks = (N + 3) / 4;
    int nlin_blocks = (N + 63) / 64;
    int nbin_blocks = (E + CHUNK - 1) / CHUNK;

    hipMemsetAsync(bucketCursor, 0, (size_t)nb * 4, stream);

    kA_bin<<<nbin_blocks, BINT, 0, stream>>>(src, dst, E, bucketCursor, binned, nb,
                                             (unsigned short*)hh, N);
    kB_place<<<nb, 256, 0, stream>>>(binned, bucketCursor, meta, dinv, csr, N);

    k_linear<<<nlin_blocks, 256, 0, stream>>>(x0, DIM, W1, dinv, hh, N);
    k_gather<<<nrow_blocks, 256, 0, stream>>>(meta, csr, (const char*)hh, b1, out, 0, N);

    k_linear<<<nlin_blocks, 256, 0, stream>>>(out, 128, W2, dinv, hh, N);
    k_gather<<<nrow_blocks, 256, 0, stream>>>(meta, csr, (const char*)hh, b2, out, 64, N);
}

// Round 15
// 276.277 us; speedup vs baseline: 1.0750x; 1.0750x over previous
//
#include <hip/hip_runtime.h>
#include <hip/hip_bf16.h>

#define DIM 64
#define NEG 0.01f
#define CHUNK 8192
#define BINT 512
#define NBMAX 640   // >= ceil(150000/256) = 586 buckets
#define CAP 9216    // fixed slots per bucket (mean 6827 + pad, sigma ~85 -> big margin)

// exclusive scan of in[0..n) -> out[0..n), tmp[T] scratch, T threads
template <int T>
__device__ __forceinline__ void block_exscan(int* __restrict__ in, int* __restrict__ out,
                                             int* __restrict__ tmp, int n, int tid) {
    int carry = 0;
    for (int base = 0; base < n; base += T) {
        int i = base + tid;
        int v = (i < n) ? in[i] : 0;
        tmp[tid] = v;
        __syncthreads();
        for (int o = 1; o < T; o <<= 1) {
            int u = (tid >= o) ? tmp[tid - o] : 0;
            __syncthreads();
            tmp[tid] += u;
            __syncthreads();
        }
        if (i < n) out[i] = carry + tmp[tid] - v;
        carry += tmp[T - 1];
        __syncthreads();
    }
}

__device__ __forceinline__ float bflo(unsigned int u) { return __uint_as_float(u << 16); }
__device__ __forceinline__ float bfhi(unsigned int u) { return __uint_as_float(u & 0xFFFF0000u); }

// --- bin edges into fixed per-bucket regions (bucket = dst>>8), packed (dlow<<24 | src);
//     block 0 also zeroes the sentinel hh row ---
__global__ void kA_bin(const int* __restrict__ src, const int* __restrict__ dst, int E,
                       int* __restrict__ bucketCursor, int* __restrict__ binned, int nb,
                       unsigned short* __restrict__ hhRaw, int N) {
    __shared__ int bCnt[NBMAX];
    __shared__ int bBase[NBMAX];
    __shared__ int bGBase[NBMAX];
    __shared__ int tmp[BINT];
    __shared__ int stP[CHUNK];
    __shared__ unsigned short stB[CHUNK];
    int tid = threadIdx.x;
    if (blockIdx.x == 0 && tid < 64) hhRaw[(size_t)N * 64 + tid] = 0;  // sentinel zero row
    int e0 = blockIdx.x * CHUNK;
    int nE = min(CHUNK, E - e0);
    int nI4 = nE >> 2;
    int rem = nE & 3;
    const int4* s4 = (const int4*)(src + e0);
    const int4* d4 = (const int4*)(dst + e0);

    for (int b = tid; b < nb; b += BINT) bCnt[b] = 0;
    __syncthreads();
    for (int i = tid; i < nI4; i += BINT) {
        int4 d = d4[i];
        atomicAdd(&bCnt[d.x >> 8], 1);
        atomicAdd(&bCnt[d.y >> 8], 1);
        atomicAdd(&bCnt[d.z >> 8], 1);
        atomicAdd(&bCnt[d.w >> 8], 1);
    }
    if (tid < rem) atomicAdd(&bCnt[dst[e0 + (nI4 << 2) + tid] >> 8], 1);
    __syncthreads();
    block_exscan<BINT>(bCnt, bBase, tmp, nb, tid);
    for (int b = tid; b < nb; b += BINT) {
        int c = bCnt[b];
        if (c) bGBase[b] = atomicAdd(&bucketCursor[b], c);
        bCnt[b] = 0;
    }
    __syncthreads();
    for (int i = tid; i < nI4; i += BINT) {
        int4 s = s4[i];
        int4 d = d4[i];
#define PLACE1(SS, DD) { int b_ = (DD) >> 8; int r_ = atomicAdd(&bCnt[b_], 1); \
                         int p_ = bBase[b_] + r_; stP[p_] = (((DD) & 255) << 24) | (SS); \
                         stB[p_] = (unsigned short)b_; }
        PLACE1(s.x, d.x) PLACE1(s.y, d.y) PLACE1(s.z, d.z) PLACE1(s.w, d.w)
    }
    if (tid < rem) {
        int e = e0 + (nI4 << 2) + tid;
        int s = src[e], d = dst[e];
        PLACE1(s, d)
    }
#undef PLACE1
    __syncthreads();
    for (int i = tid; i < nE; i += BINT) {
        int b = stB[i];
        int rel = bGBase[b] + (i - bBase[b]);
        if (rel < CAP) binned[(size_t)b * CAP + rel] = stP[i];
    }
}

// --- per-bucket place: LDS-staged; emits meta{begIdx,paddedCnt,dinv}, dinv, padded csr ---
__global__ void kB_place(const int* __restrict__ binned, const int* __restrict__ bucketCursor,
                         int4* __restrict__ meta, float* __restrict__ dinv,
                         int* __restrict__ csr, int N) {
    __shared__ int st[CAP];
    __shared__ int nodeCnt[256];
    __shared__ int nodeOff[256];
    __shared__ int tmp[256];
    int tid = threadIdx.x;
    int b = blockIdx.x;
    int cntE = min(bucketCursor[b], CAP);
    const int* bb = binned + (size_t)b * CAP;
    for (int e = tid; e < cntE; e += 256) st[e] = bb[e];
    nodeCnt[tid] = 0;
    __syncthreads();
    for (int e = tid; e < cntE; e += 256) atomicAdd(&nodeCnt[((unsigned int)st[e]) >> 24], 1);
    __syncthreads();
    int myc = nodeCnt[tid];
    int mypc = (myc + 7) & ~7;  // pad rows to multiple of 8
    nodeCnt[tid] = mypc;
    __syncthreads();
    block_exscan<256>(nodeCnt, nodeOff, tmp, 256, tid);
    int myoff = nodeOff[tid];
    int node = (b << 8) + tid;
    int base = b * CAP;
    if (node < N) {
        float dv = rsqrtf((float)myc + 1.0f);
        dinv[node] = dv;
        meta[node] = make_int4(base + myoff, mypc, __float_as_int(dv), 0);
        for (int q = myc; q < mypc; ++q) csr[base + myoff + q] = N << 7;  // sentinel -> zero row
    }
    __syncthreads();
    for (int e = tid; e < cntE; e += 256) {
        unsigned int p = (unsigned int)st[e];
        int r = atomicAdd(&nodeOff[p >> 24], 1);
        csr[base + r] = (int)(p & 0xFFFFFF) << 7;
    }
}

// --- hh(bf16) = (x @ W) * dinv[row]; LDS-tiled 4x4/thread (round-13, proven) ---
#define XSP 68
__global__ void __launch_bounds__(256, 4) k_linear(
                         const float* __restrict__ x, int xstride,
                         const float* __restrict__ W, const float* __restrict__ dinv,
                         __hip_bfloat16* __restrict__ hh, int N) {
    __shared__ float Ws[DIM][DIM];   // 16 KB
    __shared__ float xs[64][XSP];    // 17 KB (padded)
    int t = threadIdx.x;
    int row0 = blockIdx.x * 64;
#pragma unroll
    for (int k = 0; k < 16; ++k) {
        int idx = t + k * 256;
        Ws[idx >> 6][idx & 63] = W[idx];
    }
#pragma unroll
    for (int g = 0; g < 16; ++g) {
        int r = (t >> 6) + g * 4;
        int row = row0 + r;
        xs[r][t & 63] = (row < N) ? x[(size_t)row * xstride + (t & 63)] : 0.f;
    }
    __syncthreads();

    int c0 = (t & 15) * 4;
    int r0 = (t >> 4) * 4;
    float4 accR0 = {0.f, 0.f, 0.f, 0.f};
    float4 accR1 = {0.f, 0.f, 0.f, 0.f};
    float4 accR2 = {0.f, 0.f, 0.f, 0.f};
    float4 accR3 = {0.f, 0.f, 0.f, 0.f};

#define ROWFMA(ACC, XV) \
    ACC.x = fmaf(XV.x, w0.x, ACC.x); ACC.y = fmaf(XV.x, w0.y, ACC.y); \
    ACC.z = fmaf(XV.x, w0.z, ACC.z); ACC.w = fmaf(XV.x, w0.w, ACC.w); \
    ACC.x = fmaf(XV.y, w1.x, ACC.x); ACC.y = fmaf(XV.y, w1.y, ACC.y); \
    ACC.z = fmaf(XV.y, w1.z, ACC.z); ACC.w = fmaf(XV.y, w1.w, ACC.w); \
    ACC.x = fmaf(XV.z, w2.x, ACC.x); ACC.y = fmaf(XV.z, w2.y, ACC.y); \
    ACC.z = fmaf(XV.z, w2.z, ACC.z); ACC.w = fmaf(XV.z, w2.w, ACC.w); \
    ACC.x = fmaf(XV.w, w3.x, ACC.x); ACC.y = fmaf(XV.w, w3.y, ACC.y); \
    ACC.z = fmaf(XV.w, w3.z, ACC.z); ACC.w = fmaf(XV.w, w3.w, ACC.w);

#pragma unroll 1
    for (int k4 = 0; k4 < 16; ++k4) {
        int k = k4 * 4;
        float4 xv0 = *(const float4*)&xs[r0 + 0][k];
        float4 xv1 = *(const float4*)&xs[r0 + 1][k];
        float4 xv2 = *(const float4*)&xs[r0 + 2][k];
        float4 xv3 = *(const float4*)&xs[r0 + 3][k];
        float4 w0 = *(const float4*)&Ws[k + 0][c0];
        float4 w1 = *(const float4*)&Ws[k + 1][c0];
        float4 w2 = *(const float4*)&Ws[k + 2][c0];
        float4 w3 = *(const float4*)&Ws[k + 3][c0];
        ROWFMA(accR0, xv0)
        ROWFMA(accR1, xv1)
        ROWFMA(accR2, xv2)
        ROWFMA(accR3, xv3)
    }
#undef ROWFMA

#define WRITEROW(ACC, J) { \
    int row = row0 + r0 + J; \
    if (row < N) { \
        float dv = dinv[row]; \
        ushort4 o; \
        o.x = (unsigned short)(__bfloat16_as_ushort(__float2bfloat16(ACC.x * dv))); \
        o.y = (unsigned short)(__bfloat16_as_ushort(__float2bfloat16(ACC.y * dv))); \
        o.z = (unsigned short)(__bfloat16_as_ushort(__float2bfloat16(ACC.z * dv))); \
        o.w = (unsigned short)(__bfloat16_as_ushort(__float2bfloat16(ACC.w * dv))); \
        *(ushort4*)((char*)hh + (size_t)row * 128 + c0 * 2) = o; \
    } }
    WRITEROW(accR0, 0)
    WRITEROW(accR1, 1)
    WRITEROW(accR2, 2)
    WRITEROW(accR3, 3)
#undef WRITEROW
}

// --- gather (round-13 proven): select-free, sentinel-padded; lane li -> features {2li,2li+1} ---
__global__ void k_gather(const int4* __restrict__ meta, const int* __restrict__ csr,
                         const char* __restrict__ hhB, const float* __restrict__ bias,
                         float* __restrict__ out, int colOff, int N) {
    int node = blockIdx.x * 4 + (threadIdx.x >> 6);
    if (node >= N) return;
    int lane = threadIdx.x & 63;
    int half = lane >> 5;
    int li = lane & 31;
    int4 m = meta[node];
    int beg = m.x;
    int pc = m.y;
    float di = __int_as_float(m.z);
    int fo = li << 2;

    unsigned int su = *(const unsigned int*)(hhB + ((size_t)node << 7) + fo);
    float ax0 = half ? 0.f : bflo(su);
    float ay0 = half ? 0.f : bfhi(su);
    float ax1 = 0.f, ay1 = 0.f;

    const int2* p = (const int2*)(csr + beg) + half;
    int k = 0;
    for (; k + 16 <= pc; k += 16) {
        int2 iA = p[0], iB = p[2], iC = p[4], iD = p[6];
        p += 8;
        unsigned int u0 = *(const unsigned int*)(hhB + (unsigned int)iA.x + fo);
        unsigned int u1 = *(const unsigned int*)(hhB + (unsigned int)iA.y + fo);
        unsigned int u2 = *(const unsigned int*)(hhB + (unsigned int)iB.x + fo);
        unsigned int u3 = *(const unsigned int*)(hhB + (unsigned int)iB.y + fo);
        unsigned int u4 = *(const unsigned int*)(hhB + (unsigned int)iC.x + fo);
        unsigned int u5 = *(const unsigned int*)(hhB + (unsigned int)iC.y + fo);
        unsigned int u6 = *(const unsigned int*)(hhB + (unsigned int)iD.x + fo);
        unsigned int u7 = *(const unsigned int*)(hhB + (unsigned int)iD.y + fo);
        ax0 += bflo(u0) + bflo(u1);
        ay0 += bfhi(u0) + bfhi(u1);
        ax1 += bflo(u2) + bflo(u3);
        ay1 += bfhi(u2) + bfhi(u3);
        ax0 += bflo(u4) + bflo(u5);
        ay0 += bfhi(u4) + bfhi(u5);
        ax1 += bflo(u6) + bflo(u7);
        ay1 += bfhi(u6) + bfhi(u7);
    }
    if (k < pc) {
        int2 iA = p[0], iB = p[2];
        unsigned int u0 = *(const unsigned int*)(hhB + (unsigned int)iA.x + fo);
        unsigned int u1 = *(const unsigned int*)(hhB + (unsigned int)iA.y + fo);
        unsigned int u2 = *(const unsigned int*)(hhB + (unsigned int)iB.x + fo);
        unsigned int u3 = *(const unsigned int*)(hhB + (unsigned int)iB.y + fo);
        ax0 += bflo(u0) + bflo(u1);
        ay0 += bfhi(u0) + bfhi(u1);
        ax1 += bflo(u2) + bflo(u3);
        ay1 += bfhi(u2) + bfhi(u3);
    }
    float ax = ax0 + ax1;
    float ay = ay0 + ay1;
    ax += __shfl_xor(ax, 32);
    ay += __shfl_xor(ay, 32);
    if (!half) {
        float2 bb = ((const float2*)bias)[li];
        float vx = ax * di + bb.x;
        float vy = ay * di + bb.y;
        vx = vx > 0.f ? vx : vx * NEG;
        vy = vy > 0.f ? vy : vy * NEG;
        *(float2*)(out + (size_t)node * 128 + colOff + 2 * li) = make_float2(vx, vy);
    }
}

extern "C" void kernel_launch(void* const* d_in, const int* in_sizes, int n_in,
                              void* d_out, int out_size, void* d_ws, size_t ws_size,
                              hipStream_t stream) {
    const int* edge = (const int*)d_in[0];
    const float* x0 = (const float*)d_in[1];
    const float* W1 = (const float*)d_in[2];
    const float* b1 = (const float*)d_in[3];
    const float* W2 = (const float*)d_in[4];
    const float* b2 = (const float*)d_in[5];
    float* out = (float*)d_out;

    int E = in_sizes[0] / 2;
    int N = in_sizes[1] / DIM;
    const int* src = edge;
    const int* dst = edge + E;
    int nb = (N + 255) >> 8;

    char* p = (char*)d_ws;
    auto alloc = [&](size_t bytes) {
        char* r = p;
        p += (bytes + 255) & ~(size_t)255;
        return r;
    };
    int* bucketCursor = (int*)alloc((size_t)nb * 4);
    float* dinv       = (float*)alloc((size_t)N * 4);
    int4* meta        = (int4*)alloc((size_t)N * 16);
    int* csr          = (int*)alloc((size_t)nb * CAP * 4);
    int* binned       = (int*)alloc((size_t)nb * CAP * 4);
    __hip_bfloat16* hh = (__hip_bfloat16*)alloc(((size_t)N + 1) * DIM * 2);

    int nrow_blocks = (N + 3) / 4;
    int nlin_blocks = (N + 63) / 64;
    int nbin_blocks = (E + CHUNK - 1) / CHUNK;

    hipMemsetAsync(bucketCursor, 0, (size_t)nb * 4, stream);

    kA_bin<<<nbin_blocks, BINT, 0, stream>>>(src, dst, E, bucketCursor, binned, nb,
                                             (unsigned short*)hh, N);
    kB_place<<<nb, 256, 0, stream>>>(binned, bucketCursor, meta, dinv, csr, N);

    k_linear<<<nlin_blocks, 256, 0, stream>>>(x0, DIM, W1, dinv, hh, N);
    k_gather<<<nrow_blocks, 256, 0, stream>>>(meta, csr, (const char*)hh, b1, out, 0, N);

    k_linear<<<nlin_blocks, 256, 0, stream>>>(out, 128, W2, dinv, hh, N);
    k_gather<<<nrow_blocks, 256, 0, stream>>>(meta, csr, (const char*)hh, b2, out, 64, N);
}